// Round 16
// baseline (220.493 us; speedup 1.0000x reference)
//
#include <hip/hip_runtime.h>
#include <math.h>

#define NROWS 65536
#define DDIM  64
#define KCODE 4096
#define NSPLIT 4
#define KSPL  (KCODE / NSPLIT)
#define STEPS32 (KSPL / 32)        // 32

// output layout (float offsets), concatenated in reference return order
#define O_Q    0           // quantized_st [B,T,D] = 4194304
#define O_LOSS 4194304     // loss scalar
#define O_IDX  4194305     // encoding_indices [B,T] = 65536 (floats)
#define O_NW   4259841     // new_weight [K,D] = 262144
#define O_CS   4521985     // cs [K] = 4096
#define O_NEW  4526081     // new_ema_w [K,D] = 262144

// scratch inside O_Q (consumed by scatter/dw BEFORE gather2 overwrites Q):
//   E     : halves [0, 524288) — 32-code tile order, 4096 halves (8KB)/tile:
//           pos = (k>>5)*4096 + (j>>4)*512 + (((j>>3)&1)*32 + (k&31))*8 + (j&7)
//           hi at pos, lo at pos+2048
//   A     : floats [262144, 327680)   (also absorbs argmin prefetch overrun)
//   B2    : floats [327680, 331776)
//   counts: u32 @ 1000000; offs: u32 @ 1010000; cursor: u32 @ 1020000
//   order : u32 @ 1030000; lp64: double[64] @ float offset 1100000 (8B-aligned)
// scratch inside O_NW (clobbered only by vq_final, which runs LAST):
//   keys  : u64[65536] at float offset O_NW+1
#define O_A      262144
#define O_B2     327680
#define O_CNT   1000000
#define O_OFF   1010000
#define O_CUR   1020000
#define O_ORD   1030000
#define O_LP64  1100000

typedef _Float16 f16x8  __attribute__((ext_vector_type(8)));
typedef float    f32x16 __attribute__((ext_vector_type(16)));

// ---------------- Kernel A: init + splits + norms + key/count init ----------------
__global__ __launch_bounds__(256)
void vq_prep(const float* __restrict__ x, const float* __restrict__ w,
             float* __restrict__ out, unsigned long long* __restrict__ keys) {
    int i = blockIdx.x * 256 + threadIdx.x;   // grid = 262144 threads exactly
    // 32-code fragment-tile table for mfma_32x32x16: lane l of a tile holds
    // code (l&31), k = ks*16 + (l>>5)*8 + e  ->  element (code k_, kdim j):
    {
        const int k = i >> 6, j = i & 63;
        float E = w[i] * 4096.0f;             // scaled f16 split of codes
        _Float16 h = (_Float16)E;
        float r = E - (float)h;
        _Float16 lo = (_Float16)(r * 4096.0f);
        const size_t pos = (size_t)(k >> 5) * 4096 + (size_t)(j >> 4) * 512
                         + (size_t)((((j >> 3) & 1) << 5) | (k & 31)) * 8
                         + (size_t)(j & 7);
        ((_Float16*)out)[pos] = h;            // hi half of tile block
        ((_Float16*)out)[pos + 2048] = lo;    // lo half of tile block
    }
    if (i < NROWS) keys[i] = 0xFFFFFFFFFFFFFFFFULL;
    if (i < KCODE) ((unsigned*)(out + O_CNT))[i] = 0u;
    // x-norms (EXACT same per-row summation order as validated rounds)
    if ((i & 3) == 0) {
        const int row = i >> 2;
        const float4* xr = (const float4*)(x + (size_t)row * DDIM);
        float ax = 0.f, ay = 0.f, az = 0.f, aw = 0.f;
        #pragma unroll
        for (int j = 0; j < 16; ++j) {
            float4 v = xr[j];
            ax += v.x * v.x; ay += v.y * v.y; az += v.z * v.z; aw += v.w * v.w;
        }
        out[O_A + row] = (ax + ay) + (az + aw);
    }
    // w-norms
    if ((i & 63) == 0) {
        const int k = i >> 6;
        const float4* wr = (const float4*)(w + (size_t)k * DDIM);
        float ax = 0.f, ay = 0.f, az = 0.f, aw = 0.f;
        #pragma unroll
        for (int j = 0; j < 16; ++j) {
            float4 v = wr[j];
            ax += v.x * v.x; ay += v.y * v.y; az += v.z * v.z; aw += v.w * v.w;
        }
        out[O_B2 + k] = (ax + ay) + (az + aw);
    }
}

__device__ inline void split8(float4 a, float4 b, f16x8& hi, f16x8& lo) {
    float vv[8] = {a.x, a.y, a.z, a.w, b.x, b.y, b.z, b.w};
    #pragma unroll
    for (int j = 0; j < 8; ++j) {
        float X = vv[j] * 256.0f;           // x*2^8
        _Float16 h = (_Float16)X;
        float r = X - (float)h;             // exact (Sterbenz)
        hi[j] = h;
        lo[j] = (_Float16)(r * 4096.0f);    // residual*2^12
    }
}

// ---------------- Kernel B: MFMA fused score + argmin (32x32x16 shape) ----------------
// grid (512, 4) x 256 thr (4 waves). Wave owns 32 rows; scans KSPL=1024 codes
// in 32 steps of 32. Rationale (r8-r15 counters): MFMA executes ON the SIMD
// vector unit, so MFMA-cycles and VALU-cycles ADD; 32x32x16 cuts MFMA cycles
// 14% (2382 vs 2075 TF) and halves MFMA instruction count + loop iterations.
// Fragment layout: lane l holds entity (l&31), k = ks*16 + (l>>5)*8 + e (same
// entity x k family as the validated 16x16x32); C/D: col=lane&31,
// row=(v&3)+8*(v>>2)+4*(lane>>5) [HW-measured m74/m101].
__global__ __launch_bounds__(256, 2)
void vq_argmin_mfma(const float* __restrict__ x,
                    const _Float16* __restrict__ etab,
                    const float* __restrict__ Ag,
                    const float* __restrict__ b2g,
                    unsigned long long* __restrict__ keys) {
    __shared__ __align__(16) float b2sh[KSPL + 128];  // pad absorbs dead prefetch reads
    const int tid = threadIdx.x;
    const int k0  = blockIdx.y * KSPL;
    ((float4*)b2sh)[tid] = ((const float4*)(b2g + k0))[tid];
    __syncthreads();

    const int l   = tid & 63;
    const int w   = tid >> 6;
    const int c32 = l & 31;
    const int hb  = l >> 5;
    const int rowbase = blockIdx.x * 128 + w * 32;

    // A fragments: row rowbase+c32, frag ks covers k = ks*16 + hb*8 + {0..7}
    f16x8 xh[4], xl[4];
    {
        const float* xr = x + (size_t)(rowbase + c32) * DDIM + hb * 8;
        #pragma unroll
        for (int ks = 0; ks < 4; ++ks) {
            float4 a0 = *(const float4*)(xr + ks * 16);
            float4 a1 = *(const float4*)(xr + ks * 16 + 4);
            split8(a0, a1, xh[ks], xl[ks]);
        }
    }
    // per-lane epilogue rows: (v&3) + 8*(v>>2) + 4*hb
    float A_reg[16];
    #pragma unroll
    for (int v = 0; v < 16; ++v)
        A_reg[v] = Ag[rowbase + (v & 3) + 8 * (v >> 2) + 4 * hb];

    float bestv[16]; int bidx[16];
    #pragma unroll
    for (int v = 0; v < 16; ++v) { bestv[v] = INFINITY; bidx[v] = 0; }

    // tile t block at t*4096 halves; lane fragment at +l*8; hi frags at
    // ks*512, lo at 2048+ks*512
    const _Float16* p[2];
    p[0] = etab + (size_t)(k0 >> 5) * 4096 + (size_t)l * 8;
    p[1] = p[0] + 4096;

    f16x8 BH[2][4], BL[2][4];
    float b2r[2];
    int b2i[2] = {c32, 32 + c32};             // padded b2sh: no wrap mask
    int cbase = k0 + c32;                     // strictly increasing code index
    const f32x16 fzero = {0.f,0.f,0.f,0.f,0.f,0.f,0.f,0.f,
                          0.f,0.f,0.f,0.f,0.f,0.f,0.f,0.f};

#define LOADB(sl) do {                                        \
        _Pragma("unroll")                                     \
        for (int ks = 0; ks < 4; ++ks) {                      \
            BH[sl][ks] = *(const f16x8*)(p[sl] + ks * 512);   \
            BL[sl][ks] = *(const f16x8*)(p[sl] + 2048 + ks * 512); \
        }                                                     \
        b2r[sl] = b2sh[b2i[sl]];                              \
        p[sl] += 8192;                                        \
        b2i[sl] += 64;                                        \
    } while (0)

#define COMP(sl) do {                                                             \
        f32x16 a1, a2;                                                            \
        a1 = __builtin_amdgcn_mfma_f32_32x32x16_f16(xh[0], BH[sl][0], fzero, 0, 0, 0); \
        a1 = __builtin_amdgcn_mfma_f32_32x32x16_f16(xh[1], BH[sl][1], a1,    0, 0, 0); \
        a1 = __builtin_amdgcn_mfma_f32_32x32x16_f16(xh[2], BH[sl][2], a1,    0, 0, 0); \
        a1 = __builtin_amdgcn_mfma_f32_32x32x16_f16(xh[3], BH[sl][3], a1,    0, 0, 0); \
        a2 = __builtin_amdgcn_mfma_f32_32x32x16_f16(xl[0], BH[sl][0], fzero, 0, 0, 0); \
        a2 = __builtin_amdgcn_mfma_f32_32x32x16_f16(xl[1], BH[sl][1], a2,    0, 0, 0); \
        a2 = __builtin_amdgcn_mfma_f32_32x32x16_f16(xl[2], BH[sl][2], a2,    0, 0, 0); \
        a2 = __builtin_amdgcn_mfma_f32_32x32x16_f16(xl[3], BH[sl][3], a2,    0, 0, 0); \
        a2 = __builtin_amdgcn_mfma_f32_32x32x16_f16(xh[0], BL[sl][0], a2,    0, 0, 0); \
        a2 = __builtin_amdgcn_mfma_f32_32x32x16_f16(xh[1], BL[sl][1], a2,    0, 0, 0); \
        a2 = __builtin_amdgcn_mfma_f32_32x32x16_f16(xh[2], BL[sl][2], a2,    0, 0, 0); \
        a2 = __builtin_amdgcn_mfma_f32_32x32x16_f16(xh[3], BL[sl][3], a2,    0, 0, 0); \
        _Pragma("unroll")                                                         \
        for (int v = 0; v < 16; ++v) {                                            \
            float dotc = fmaf(a2[v], 0x1p-12f, a1[v]);                            \
            float t = A_reg[v] + b2r[sl];                                         \
            float sc = fmaf(dotc, -0x1p-19f, t);                                  \
            bool lt = sc < bestv[v];      /* strict <: lowest idx on tie */       \
            bestv[v] = lt ? sc : bestv[v];                                        \
            bidx[v]  = lt ? cbase : bidx[v];                                      \
        }                                                                         \
        cbase += 32;                                                              \
    } while (0)

    LOADB(0);
    LOADB(1);

    #pragma unroll 1
    for (int s = 0; s < STEPS32; s += 2) {
        COMP(0);
        LOADB(0);       // prefetch s+2 (overrun reads land in A-region: harmless)
        COMP(1);
        LOADB(1);       // prefetch s+3
    }
#undef LOADB
#undef COMP

    // reduce (value, then lowest index) across the 32 lanes of each half
    // (each row lives in one 32-lane half at a fixed reg v; xor<32 stays in-half)
    #pragma unroll
    for (int off2 = 1; off2 < 32; off2 <<= 1) {
        #pragma unroll
        for (int v = 0; v < 16; ++v) {
            float ob = __shfl_xor(bestv[v], off2);
            int   oi = __shfl_xor(bidx[v], off2);
            if (ob < bestv[v] || (ob == bestv[v] && oi < bidx[v])) {
                bestv[v] = ob; bidx[v] = oi;
            }
        }
    }
    if (c32 == 0) {
        #pragma unroll
        for (int v = 0; v < 16; ++v) {
            const int row = rowbase + (v & 3) + 8 * (v >> 2) + 4 * hb;
            unsigned long long key =
                ((unsigned long long)__float_as_uint(bestv[v]) << 32) |
                (unsigned)bidx[v];
            atomicMin(&keys[row], key);
        }
    }
}

// ---------------- Kernel H: histogram + per-block loss partials from key scores ----------------
__global__ __launch_bounds__(1024)
void vq_hist(const unsigned long long* __restrict__ keys,
             unsigned* __restrict__ counts, double* __restrict__ lp64) {
    __shared__ unsigned h[KCODE];
    __shared__ double dsh[16];
    const int tid = threadIdx.x;
    #pragma unroll
    for (int j = 0; j < 4; ++j) h[tid + j * 1024] = 0u;
    __syncthreads();
    const int row = blockIdx.x * 1024 + tid;      // grid 64 x 1024
    const unsigned long long kk = keys[row];
    const unsigned k = (unsigned)(kk & 0xFFFFFFFFu);
    float sc = __uint_as_float((unsigned)(kk >> 32));   // row's min score = ||x-w_k||^2
    atomicAdd(&h[k], 1u);
    #pragma unroll
    for (int off = 32; off > 0; off >>= 1) sc += __shfl_down(sc, off);
    if ((tid & 63) == 0) dsh[tid >> 6] = (double)sc;
    __syncthreads();
    if (tid == 0) {
        double s = 0.0;
        #pragma unroll
        for (int i = 0; i < 16; ++i) s += dsh[i];
        lp64[blockIdx.x] = s;
    }
    #pragma unroll
    for (int j = 0; j < 4; ++j) {
        unsigned v = h[tid + j * 1024];
        if (v) atomicAdd(&counts[tid + j * 1024], v);
    }
}

// ---------------- Kernel S: scan -> offsets/cursor + smoothed cs + loss ----------------
__global__ __launch_bounds__(1024)
void vq_scan_cs(const unsigned* __restrict__ counts, const float* __restrict__ ecs,
                const double* __restrict__ lp64,
                unsigned* __restrict__ offs, unsigned* __restrict__ cursor,
                float* __restrict__ out) {
    __shared__ unsigned red[1024];
    __shared__ float fred[1024];
    const int tid = threadIdx.x;
    unsigned c[4]; float csv[4];
    unsigned tot = 0; float fl = 0.f;
    #pragma unroll
    for (int j = 0; j < 4; ++j) {
        const int k = tid * 4 + j;
        c[j] = counts[k];
        tot += c[j];
        csv[j] = ecs[k] * 0.99f + 0.01f * (float)c[j];
        fl += csv[j];
    }
    red[tid] = tot; fred[tid] = fl;
    __syncthreads();
    for (int s = 1; s < 1024; s <<= 1) {
        unsigned v = (tid >= s) ? red[tid - s] : 0u;
        float  fv = (tid >= s) ? fred[tid - s] : 0.f;
        __syncthreads();
        red[tid] += v; fred[tid] += fv;
        __syncthreads();
    }
    const float n = fred[1023];
    unsigned base = red[tid] - tot;   // exclusive prefix
    const float denom = n + 0.04096f; // n + K*EPS
    #pragma unroll
    for (int j = 0; j < 4; ++j) {
        const int k = tid * 4 + j;
        offs[k] = base; cursor[k] = base; base += c[j];
        out[O_CS + k] = (csv[j] + 1e-5f) / denom * n;
    }
    if (tid == 0) {
        double dl = 0.0;
        for (int i = 0; i < 64; ++i) dl += lp64[i];
        out[O_LOSS] = 1.25f * (float)(dl / 4194304.0);
    }
}

// ---------------- Kernel T: scatter row ids into code-sorted order ----------------
__global__ __launch_bounds__(256)
void vq_scatter(const unsigned long long* __restrict__ keys,
                unsigned* __restrict__ cursor, unsigned* __restrict__ order) {
    const int row = blockIdx.x * 256 + threadIdx.x;
    const unsigned k = (unsigned)(keys[row] & 0xFFFFFFFFu);
    const unsigned slot = atomicAdd(&cursor[k], 1u);
    order[slot] = row;
}

// ---------------- Kernel W: per-code segment sum -> new_ema_w ----------------
__global__ __launch_bounds__(256)
void vq_dw(const float* __restrict__ x, const float* __restrict__ ema_w,
           const unsigned* __restrict__ counts, const unsigned* __restrict__ offs,
           const unsigned* __restrict__ order, float* __restrict__ out) {
    const int tid = threadIdx.x;
    const int lane = tid & 63;
    const int k = blockIdx.x * 4 + (tid >> 6);    // grid 1024 x 256
    const unsigned cnt = counts[k];
    const unsigned off = offs[k];
    float acc = 0.f;
    for (unsigned i = 0; i < cnt; ++i) {
        const unsigned row = order[off + i];
        acc += x[(size_t)row * DDIM + lane];
    }
    const float e = ema_w[(size_t)k * DDIM + lane];
    out[O_NEW + (size_t)k * DDIM + lane] = fmaf(0.01f, acc, 0.99f * e);
}

// ---------------- Kernel C: gather + ST output (pure streaming) ----------------
__global__ __launch_bounds__(256)
void vq_gather2(const float* __restrict__ x, const float* __restrict__ w,
                const unsigned long long* __restrict__ keys,
                float* __restrict__ out) {
    const int tid = threadIdx.x;
    const int l16 = tid & 15;
    const int row = blockIdx.x * 16 + (tid >> 4);
    const int k = (int)(unsigned)(keys[row] & 0xFFFFFFFFu);
    if (l16 == 0) out[O_IDX + row] = (float)k;
    const float4 w4 = ((const float4*)(w + (size_t)k * DDIM))[l16];
    const float4 x4 = ((const float4*)(x + (size_t)row * DDIM))[l16];
    float4 o;
    o.x = x4.x + (w4.x - x4.x);
    o.y = x4.y + (w4.y - x4.y);
    o.z = x4.z + (w4.z - x4.z);
    o.w = x4.w + (w4.w - x4.w);
    ((float4*)(out + O_Q + (size_t)row * DDIM))[l16] = o;
}

// ---------------- Kernel E: new_weight = new_ema_w / cs (LAST; clobbers keys) ----------------
__global__ __launch_bounds__(256)
void vq_final(float* __restrict__ out) {
    int i = blockIdx.x * 256 + threadIdx.x;
    if (i >= KCODE * DDIM) return;
    int k = i >> 6;
    out[O_NW + i] = out[O_NEW + i] / out[O_CS + k];
}

extern "C" void kernel_launch(void* const* d_in, const int* in_sizes, int n_in,
                              void* d_out, int out_size, void* d_ws, size_t ws_size,
                              hipStream_t stream) {
    (void)in_sizes; (void)n_in; (void)out_size; (void)d_ws; (void)ws_size;
    const float* x    = (const float*)d_in[0];
    const float* w    = (const float*)d_in[1];
    const float* ecs  = (const float*)d_in[2];
    const float* emaw = (const float*)d_in[3];
    float* out = (float*)d_out;

    const _Float16* etab = (const _Float16*)out;
    const float*    Ag   = out + O_A;
    unsigned long long* keys = (unsigned long long*)(out + O_NW + 1);
    unsigned* counts = (unsigned*)(out + O_CNT);
    unsigned* offs   = (unsigned*)(out + O_OFF);
    unsigned* cursor = (unsigned*)(out + O_CUR);
    unsigned* order  = (unsigned*)(out + O_ORD);
    double*   lp64   = (double*)(out + O_LP64);

    vq_prep       <<<1024, 256, 0, stream>>>(x, w, out, keys);
    vq_argmin_mfma<<<dim3(512, NSPLIT), 256, 0, stream>>>(x, etab, Ag,
                                                          out + O_B2, keys);
    vq_hist       <<<64, 1024, 0, stream>>>(keys, counts, lp64);
    vq_scan_cs    <<<1, 1024, 0, stream>>>(counts, ecs, lp64, offs, cursor, out);
    vq_scatter    <<<256, 256, 0, stream>>>(keys, cursor, order);
    vq_dw         <<<1024, 256, 0, stream>>>(x, emaw, counts, offs, order, out);
    vq_gather2    <<<4096, 256, 0, stream>>>(x, w, keys, out);
    vq_final      <<<1024, 256, 0, stream>>>(out);
}

// Round 17
// 184.959 us; speedup vs baseline: 1.1921x; 1.1921x over previous
//
#include <hip/hip_runtime.h>
#include <math.h>

#define NROWS 65536
#define DDIM  64
#define KCODE 4096
#define NSPLIT 4
#define KSPL  (KCODE / NSPLIT)
#define STEPS (KSPL / 16)          // 64

// output layout (float offsets), concatenated in reference return order
#define O_Q    0           // quantized_st [B,T,D] = 4194304
#define O_LOSS 4194304     // loss scalar
#define O_IDX  4194305     // encoding_indices [B,T] = 65536 (floats)
#define O_NW   4259841     // new_weight [K,D] = 262144
#define O_CS   4521985     // cs [K] = 4096
#define O_NEW  4526081     // new_ema_w [K,D] = 262144

// scratch inside O_Q (consumed by scatter/dw BEFORE gather2 overwrites Q):
//   E     : halves [0, 524288) — interleaved fragment-tile order, 2048/tile
//   A     : floats [262144, 327680)   (also absorbs argmin prefetch overrun)
//   B2    : floats [327680, 331776)
//   counts: u32 @ 1000000; offs: u32 @ 1010000; cursor: u32 @ 1020000
//   order : u32 @ 1030000; lp64: double[64] @ float offset 1100000 (8B-aligned)
// scratch inside O_NW (clobbered only by vq_final, which runs LAST):
//   keys  : u64[65536] at float offset O_NW+1
#define O_A      262144
#define O_B2     327680
#define O_CNT   1000000
#define O_OFF   1010000
#define O_CUR   1020000
#define O_ORD   1030000
#define O_LP64  1100000

typedef _Float16 f16x8 __attribute__((ext_vector_type(8)));
typedef float    f32x4 __attribute__((ext_vector_type(4)));

// ---------------- Kernel A: init + splits + norms + key/count init ----------------
__global__ __launch_bounds__(256)
void vq_prep(const float* __restrict__ x, const float* __restrict__ w,
             float* __restrict__ out, unsigned long long* __restrict__ keys) {
    int i = blockIdx.x * 256 + threadIdx.x;   // grid = 262144 threads exactly
    // interleaved fragment-tile table (validated rounds 10-12)
    {
        const int k = i >> 6, j = i & 63;
        float E = w[i] * 4096.0f;             // scaled f16 split of codes
        _Float16 h = (_Float16)E;
        float r = E - (float)h;
        _Float16 lo = (_Float16)(r * 4096.0f);
        const size_t pos = (size_t)(k >> 4) * 2048 + (size_t)(j >> 5) * 512
                         + (size_t)((j >> 3) & 3) * 128 + (size_t)(k & 15) * 8
                         + (size_t)(j & 7);
        ((_Float16*)out)[pos] = h;            // hi half of tile block
        ((_Float16*)out)[pos + 1024] = lo;    // lo half of tile block
    }
    if (i < NROWS) keys[i] = 0xFFFFFFFFFFFFFFFFULL;
    if (i < KCODE) ((unsigned*)(out + O_CNT))[i] = 0u;
    // x-norms (EXACT same per-row summation order as validated rounds)
    if ((i & 3) == 0) {
        const int row = i >> 2;
        const float4* xr = (const float4*)(x + (size_t)row * DDIM);
        float ax = 0.f, ay = 0.f, az = 0.f, aw = 0.f;
        #pragma unroll
        for (int j = 0; j < 16; ++j) {
            float4 v = xr[j];
            ax += v.x * v.x; ay += v.y * v.y; az += v.z * v.z; aw += v.w * v.w;
        }
        out[O_A + row] = (ax + ay) + (az + aw);
    }
    // w-norms
    if ((i & 63) == 0) {
        const int k = i >> 6;
        const float4* wr = (const float4*)(w + (size_t)k * DDIM);
        float ax = 0.f, ay = 0.f, az = 0.f, aw = 0.f;
        #pragma unroll
        for (int j = 0; j < 16; ++j) {
            float4 v = wr[j];
            ax += v.x * v.x; ay += v.y * v.y; az += v.z * v.z; aw += v.w * v.w;
        }
        out[O_B2 + k] = (ax + ay) + (az + aw);
    }
}

__device__ inline void split8(float4 a, float4 b, f16x8& hi, f16x8& lo) {
    float vv[8] = {a.x, a.y, a.z, a.w, b.x, b.y, b.z, b.w};
    #pragma unroll
    for (int j = 0; j < 8; ++j) {
        float X = vv[j] * 256.0f;           // x*2^8
        _Float16 h = (_Float16)X;
        float r = X - (float)h;             // exact (Sterbenz)
        hi[j] = h;
        lo[j] = (_Float16)(r * 4096.0f);    // residual*2^12
    }
}

// ---------------- Kernel B: MFMA fused score + argmin (r12 structure, best validated) ----------------
// grid (512, 4) x 256 thr (4 waves). Wave owns 32 rows (R=2); scans KSPL=1024
// codes in 64 steps of 16. Single table pointer + imm offsets (interleaved
// table), padded b2sh (no mask op). Measured plateau: ~124us, MfmaUtil 37.6%,
// VALUBusy 46% — ~86% of the issue-sum bound; r11/r15/r16 restructures all
// regressed, epilogue VALU pinned by bit-exact score rounding.
__global__ __launch_bounds__(256, 3)
void vq_argmin_mfma(const float* __restrict__ x,
                    const _Float16* __restrict__ etab,
                    const float* __restrict__ Ag,
                    const float* __restrict__ b2g,
                    unsigned long long* __restrict__ keys) {
    __shared__ __align__(16) float b2sh[KSPL + 128];  // pad absorbs dead prefetch reads
    const int tid = threadIdx.x;
    const int k0  = blockIdx.y * KSPL;
    ((float4*)b2sh)[tid] = ((const float4*)(b2g + k0))[tid];
    __syncthreads();

    const int l   = tid & 63;
    const int w   = tid >> 6;
    const int g   = l >> 4;
    const int c16 = l & 15;
    const int rowbase = blockIdx.x * 128 + w * 32;

    f16x8 xh[2][2], xl[2][2];
    #pragma unroll
    for (int r = 0; r < 2; ++r) {
        const float* xr = x + (size_t)(rowbase + r * 16 + c16) * DDIM + g * 8;
        float4 a0 = *(const float4*)(xr);
        float4 a1 = *(const float4*)(xr + 4);
        float4 a2 = *(const float4*)(xr + 32);
        float4 a3 = *(const float4*)(xr + 36);
        split8(a0, a1, xh[r][0], xl[r][0]);
        split8(a2, a3, xh[r][1], xl[r][1]);
    }
    float A_reg[2][4];
    #pragma unroll
    for (int r = 0; r < 2; ++r)
        #pragma unroll
        for (int v = 0; v < 4; ++v)
            A_reg[r][v] = Ag[rowbase + r * 16 + 4 * g + v];

    float bestv[2][4]; int bidx[2][4];
    #pragma unroll
    for (int r = 0; r < 2; ++r)
        #pragma unroll
        for (int v = 0; v < 4; ++v) { bestv[r][v] = INFINITY; bidx[r][v] = 0; }

    // interleaved table: tile t block at t*2048 halves; lane fragment at +l*8
    const _Float16* p[2];
    p[0] = etab + (size_t)(k0 >> 4) * 2048 + (size_t)l * 8;
    p[1] = p[0] + 2048;

    f16x8 bh0[2], bh1[2], bl0[2], bl1[2];
    float b2r[2];
    int b2i[2] = {c16, 16 + c16};             // padded b2sh: no wrap mask
    int cbase = k0 + c16;                     // strictly increasing code index
    const f32x4 fzero = {0.f, 0.f, 0.f, 0.f};

#define LOADB(sl) do {                                       \
        bh0[sl] = *(const f16x8*)(p[sl]);                    \
        bh1[sl] = *(const f16x8*)(p[sl] + 512);              \
        bl0[sl] = *(const f16x8*)(p[sl] + 1024);             \
        bl1[sl] = *(const f16x8*)(p[sl] + 1536);             \
        b2r[sl] = b2sh[b2i[sl]];                             \
        p[sl] += 4096;                                       \
        b2i[sl] += 32;                                       \
    } while (0)

#define COMP(sl) do {                                                             \
        f32x4 acc1[2], acc2[2];                                                   \
        _Pragma("unroll")                                                         \
        for (int r = 0; r < 2; ++r) {                                             \
            acc1[r] = __builtin_amdgcn_mfma_f32_16x16x32_f16(xh[r][0], bh0[sl], fzero,   0, 0, 0); \
            acc1[r] = __builtin_amdgcn_mfma_f32_16x16x32_f16(xh[r][1], bh1[sl], acc1[r], 0, 0, 0); \
            acc2[r] = __builtin_amdgcn_mfma_f32_16x16x32_f16(xl[r][0], bh0[sl], fzero,   0, 0, 0); \
            acc2[r] = __builtin_amdgcn_mfma_f32_16x16x32_f16(xl[r][1], bh1[sl], acc2[r], 0, 0, 0); \
            acc2[r] = __builtin_amdgcn_mfma_f32_16x16x32_f16(xh[r][0], bl0[sl], acc2[r], 0, 0, 0); \
            acc2[r] = __builtin_amdgcn_mfma_f32_16x16x32_f16(xh[r][1], bl1[sl], acc2[r], 0, 0, 0); \
        }                                                                         \
        _Pragma("unroll")                                                         \
        for (int r = 0; r < 2; ++r) {                                             \
            _Pragma("unroll")                                                     \
            for (int v = 0; v < 4; ++v) {                                         \
                float dotc = fmaf(acc2[r][v], 0x1p-12f, acc1[r][v]);              \
                float t = A_reg[r][v] + b2r[sl];                                  \
                float sc = fmaf(dotc, -0x1p-19f, t);                              \
                bool lt = sc < bestv[r][v];   /* strict <: lowest idx on tie */   \
                bestv[r][v] = lt ? sc : bestv[r][v];                              \
                bidx[r][v]  = lt ? cbase : bidx[r][v];                            \
            }                                                                     \
        }                                                                         \
        cbase += 16;                                                              \
    } while (0)

    LOADB(0);
    LOADB(1);

    #pragma unroll 1
    for (int s = 0; s < STEPS; s += 2) {
        COMP(0);
        LOADB(0);       // prefetch s+2 (overrun reads land in A-region: harmless)
        COMP(1);
        LOADB(1);       // prefetch s+3
    }
#undef LOADB
#undef COMP

    // reduce (value, then lowest index) across the 16 lanes of each k-group
    #pragma unroll
    for (int off2 = 1; off2 < 16; off2 <<= 1) {
        #pragma unroll
        for (int r = 0; r < 2; ++r)
            #pragma unroll
            for (int v = 0; v < 4; ++v) {
                float ob = __shfl_xor(bestv[r][v], off2);
                int   oi = __shfl_xor(bidx[r][v], off2);
                if (ob < bestv[r][v] || (ob == bestv[r][v] && oi < bidx[r][v])) {
                    bestv[r][v] = ob; bidx[r][v] = oi;
                }
            }
    }
    if (c16 == 0) {
        #pragma unroll
        for (int r = 0; r < 2; ++r)
            #pragma unroll
            for (int v = 0; v < 4; ++v) {
                const int row = rowbase + r * 16 + 4 * g + v;
                unsigned long long key =
                    ((unsigned long long)__float_as_uint(bestv[r][v]) << 32) |
                    (unsigned)bidx[r][v];
                atomicMin(&keys[row], key);
            }
    }
}

// ---------------- Kernel H: histogram + per-block loss partials from key scores ----------------
__global__ __launch_bounds__(1024)
void vq_hist(const unsigned long long* __restrict__ keys,
             unsigned* __restrict__ counts, double* __restrict__ lp64) {
    __shared__ unsigned h[KCODE];
    __shared__ double dsh[16];
    const int tid = threadIdx.x;
    #pragma unroll
    for (int j = 0; j < 4; ++j) h[tid + j * 1024] = 0u;
    __syncthreads();
    const int row = blockIdx.x * 1024 + tid;      // grid 64 x 1024
    const unsigned long long kk = keys[row];
    const unsigned k = (unsigned)(kk & 0xFFFFFFFFu);
    float sc = __uint_as_float((unsigned)(kk >> 32));   // row's min score = ||x-w_k||^2
    atomicAdd(&h[k], 1u);
    #pragma unroll
    for (int off = 32; off > 0; off >>= 1) sc += __shfl_down(sc, off);
    if ((tid & 63) == 0) dsh[tid >> 6] = (double)sc;
    __syncthreads();
    if (tid == 0) {
        double s = 0.0;
        #pragma unroll
        for (int i = 0; i < 16; ++i) s += dsh[i];
        lp64[blockIdx.x] = s;
    }
    #pragma unroll
    for (int j = 0; j < 4; ++j) {
        unsigned v = h[tid + j * 1024];
        if (v) atomicAdd(&counts[tid + j * 1024], v);
    }
}

// ---------------- Kernel S: scan -> offsets/cursor + smoothed cs + loss ----------------
__global__ __launch_bounds__(1024)
void vq_scan_cs(const unsigned* __restrict__ counts, const float* __restrict__ ecs,
                const double* __restrict__ lp64,
                unsigned* __restrict__ offs, unsigned* __restrict__ cursor,
                float* __restrict__ out) {
    __shared__ unsigned red[1024];
    __shared__ float fred[1024];
    const int tid = threadIdx.x;
    unsigned c[4]; float csv[4];
    unsigned tot = 0; float fl = 0.f;
    #pragma unroll
    for (int j = 0; j < 4; ++j) {
        const int k = tid * 4 + j;
        c[j] = counts[k];
        tot += c[j];
        csv[j] = ecs[k] * 0.99f + 0.01f * (float)c[j];
        fl += csv[j];
    }
    red[tid] = tot; fred[tid] = fl;
    __syncthreads();
    for (int s = 1; s < 1024; s <<= 1) {
        unsigned v = (tid >= s) ? red[tid - s] : 0u;
        float  fv = (tid >= s) ? fred[tid - s] : 0.f;
        __syncthreads();
        red[tid] += v; fred[tid] += fv;
        __syncthreads();
    }
    const float n = fred[1023];
    unsigned base = red[tid] - tot;   // exclusive prefix
    const float denom = n + 0.04096f; // n + K*EPS
    #pragma unroll
    for (int j = 0; j < 4; ++j) {
        const int k = tid * 4 + j;
        offs[k] = base; cursor[k] = base; base += c[j];
        out[O_CS + k] = (csv[j] + 1e-5f) / denom * n;
    }
    if (tid == 0) {
        double dl = 0.0;
        for (int i = 0; i < 64; ++i) dl += lp64[i];
        out[O_LOSS] = 1.25f * (float)(dl / 4194304.0);
    }
}

// ---------------- Kernel T: scatter row ids into code-sorted order ----------------
__global__ __launch_bounds__(256)
void vq_scatter(const unsigned long long* __restrict__ keys,
                unsigned* __restrict__ cursor, unsigned* __restrict__ order) {
    const int row = blockIdx.x * 256 + threadIdx.x;
    const unsigned k = (unsigned)(keys[row] & 0xFFFFFFFFu);
    const unsigned slot = atomicAdd(&cursor[k], 1u);
    order[slot] = row;
}

// ---------------- Kernel W: per-code segment sum -> new_ema_w ----------------
__global__ __launch_bounds__(256)
void vq_dw(const float* __restrict__ x, const float* __restrict__ ema_w,
           const unsigned* __restrict__ counts, const unsigned* __restrict__ offs,
           const unsigned* __restrict__ order, float* __restrict__ out) {
    const int tid = threadIdx.x;
    const int lane = tid & 63;
    const int k = blockIdx.x * 4 + (tid >> 6);    // grid 1024 x 256
    const unsigned cnt = counts[k];
    const unsigned off = offs[k];
    float acc = 0.f;
    for (unsigned i = 0; i < cnt; ++i) {
        const unsigned row = order[off + i];
        acc += x[(size_t)row * DDIM + lane];
    }
    const float e = ema_w[(size_t)k * DDIM + lane];
    out[O_NEW + (size_t)k * DDIM + lane] = fmaf(0.01f, acc, 0.99f * e);
}

// ---------------- Kernel C: gather + ST output (pure streaming) ----------------
__global__ __launch_bounds__(256)
void vq_gather2(const float* __restrict__ x, const float* __restrict__ w,
                const unsigned long long* __restrict__ keys,
                float* __restrict__ out) {
    const int tid = threadIdx.x;
    const int l16 = tid & 15;
    const int row = blockIdx.x * 16 + (tid >> 4);
    const int k = (int)(unsigned)(keys[row] & 0xFFFFFFFFu);
    if (l16 == 0) out[O_IDX + row] = (float)k;
    const float4 w4 = ((const float4*)(w + (size_t)k * DDIM))[l16];
    const float4 x4 = ((const float4*)(x + (size_t)row * DDIM))[l16];
    float4 o;
    o.x = x4.x + (w4.x - x4.x);
    o.y = x4.y + (w4.y - x4.y);
    o.z = x4.z + (w4.z - x4.z);
    o.w = x4.w + (w4.w - x4.w);
    ((float4*)(out + O_Q + (size_t)row * DDIM))[l16] = o;
}

// ---------------- Kernel E: new_weight = new_ema_w / cs (LAST; clobbers keys) ----------------
__global__ __launch_bounds__(256)
void vq_final(float* __restrict__ out) {
    int i = blockIdx.x * 256 + threadIdx.x;
    if (i >= KCODE * DDIM) return;
    int k = i >> 6;
    out[O_NW + i] = out[O_NEW + i] / out[O_CS + k];
}

extern "C" void kernel_launch(void* const* d_in, const int* in_sizes, int n_in,
                              void* d_out, int out_size, void* d_ws, size_t ws_size,
                              hipStream_t stream) {
    (void)in_sizes; (void)n_in; (void)out_size; (void)d_ws; (void)ws_size;
    const float* x    = (const float*)d_in[0];
    const float* w    = (const float*)d_in[1];
    const float* ecs  = (const float*)d_in[2];
    const float* emaw = (const float*)d_in[3];
    float* out = (float*)d_out;

    const _Float16* etab = (const _Float16*)out;
    const float*    Ag   = out + O_A;
    unsigned long long* keys = (unsigned long long*)(out + O_NW + 1);
    unsigned* counts = (unsigned*)(out + O_CNT);
    unsigned* offs   = (unsigned*)(out + O_OFF);
    unsigned* cursor = (unsigned*)(out + O_CUR);
    unsigned* order  = (unsigned*)(out + O_ORD);
    double*   lp64   = (double*)(out + O_LP64);

    vq_prep       <<<1024, 256, 0, stream>>>(x, w, out, keys);
    vq_argmin_mfma<<<dim3(512, NSPLIT), 256, 0, stream>>>(x, etab, Ag,
                                                          out + O_B2, keys);
    vq_hist       <<<64, 1024, 0, stream>>>(keys, counts, lp64);
    vq_scan_cs    <<<1, 1024, 0, stream>>>(counts, ecs, lp64, offs, cursor, out);
    vq_scatter    <<<256, 256, 0, stream>>>(keys, cursor, order);
    vq_dw         <<<1024, 256, 0, stream>>>(x, emaw, counts, offs, order, out);
    vq_gather2    <<<4096, 256, 0, stream>>>(x, w, keys, out);
    vq_final      <<<1024, 256, 0, stream>>>(out);
}